// Round 13
// baseline (541.224 us; speedup 1.0000x reference)
//
#include <hip/hip_runtime.h>
#include <math.h>
#include <stdint.h>

#define N_TOK 8192
#define DMODEL 1024
#define HID 2048
#define NEXP 8
#define TOPK 2
#define CAP 2560
// pool: [0,64) G1 idx 0..63 | [64,128) W2T | [128,704) G1 idx 64..639 |
//       [704,1344) G2 idx 0..639
#define NTALL 1344

typedef __bf16 bf16x8 __attribute__((ext_vector_type(8)));
typedef float f32x4 __attribute__((ext_vector_type(4)));
typedef unsigned int u32x4 __attribute__((ext_vector_type(4)));

__device__ __forceinline__ unsigned short f2b(float f) {
    unsigned int u = __builtin_bit_cast(unsigned int, f);
    u += 0x7fffu + ((u >> 16) & 1u);           // round-to-nearest-even
    return (unsigned short)(u >> 16);
}
__device__ __forceinline__ float b2f(unsigned short s) {
    unsigned int u = ((unsigned int)s) << 16;
    return __builtin_bit_cast(float, u);
}

// Branch-free GELU via Abramowitz-Stegun 7.1.26 erf (|err| <= 1.5e-7)
__device__ __forceinline__ float gelu_f(float v) {
    const float ax = fabsf(v) * 0.70710678118654752440f;
    const float t = __builtin_amdgcn_rcpf(1.f + 0.3275911f * ax);
    float poly = ((((1.061405429f * t - 1.453152027f) * t + 1.421413741f) * t
                   - 0.284496736f) * t + 0.254829592f) * t;
    float er = 1.f - poly * __expf(-ax * ax);
    er = (v >= 0.f) ? er : -er;
    return 0.5f * v * (1.f + er);
}

// async global->LDS, 16B per lane. LDS dst is wave-uniform base (+lane*16 in HW).
__device__ __forceinline__ void gload_lds16(const void* g, void* lds) {
    __builtin_amdgcn_global_load_lds(
        (const __attribute__((address_space(1))) unsigned int*)(uintptr_t)g,
        (__attribute__((address_space(3))) unsigned int*)(unsigned int)(uintptr_t)lds,
        16, 0, 0);
}

// ---------------------------------------------------------------------------
// Gating (exact f32, summation order IDENTICAL to R1-R12 — protects routing
// tie behavior) + fused x->bf16 write.
// ---------------------------------------------------------------------------
__global__ __launch_bounds__(256) void gate_kernel(
    const float* __restrict__ x, const float* __restrict__ Wg,
    const float* __restrict__ bg,
    int* __restrict__ flat_e, float* __restrict__ flat_p,
    float* __restrict__ imp_part, float* __restrict__ sel_part,
    unsigned short* __restrict__ xbf)
{
    __shared__ float s_imp[4][NEXP];
    __shared__ float s_sel[4][NEXP];
    const int wave = threadIdx.x >> 6;
    const int lane = threadIdx.x & 63;
    const int t = blockIdx.x * 4 + wave;

    float acc[NEXP];
#pragma unroll
    for (int e = 0; e < NEXP; ++e) acc[e] = 0.f;
    const float* xr = x + (size_t)t * DMODEL;
    unsigned short* xbr = xbf + (size_t)t * DMODEL;
    for (int d = lane; d < DMODEL; d += 64) {
        const float xv = xr[d];
        xbr[d] = f2b(xv);                       // fused convert_x
#pragma unroll
        for (int e = 0; e < NEXP; ++e) acc[e] += xv * Wg[d * NEXP + e];
    }
#pragma unroll
    for (int off = 32; off > 0; off >>= 1) {
#pragma unroll
        for (int e = 0; e < NEXP; ++e) acc[e] += __shfl_xor(acc[e], off);
    }
    float lg[NEXP], mx = -1e30f;
#pragma unroll
    for (int e = 0; e < NEXP; ++e) { lg[e] = acc[e] + bg[e]; mx = fmaxf(mx, lg[e]); }
    float p[NEXP], s = 0.f;
#pragma unroll
    for (int e = 0; e < NEXP; ++e) { p[e] = expf(lg[e] - mx); s += p[e]; }
    const float inv = 1.f / s;
#pragma unroll
    for (int e = 0; e < NEXP; ++e) p[e] *= inv;

    int i0 = 0;
#pragma unroll
    for (int e = 1; e < NEXP; ++e) if (p[e] > p[i0]) i0 = e;
    int i1 = (i0 == 0) ? 1 : 0;
#pragma unroll
    for (int e = 0; e < NEXP; ++e) if (e != i0 && p[e] > p[i1]) i1 = e;

    if (lane == 0) {
        flat_e[2 * t] = i0;  flat_e[2 * t + 1] = i1;
        flat_p[2 * t] = p[i0]; flat_p[2 * t + 1] = p[i1];
#pragma unroll
        for (int e = 0; e < NEXP; ++e) {
            s_imp[wave][e] = p[e];
            s_sel[wave][e] = (e == i0) ? p[i0] : ((e == i1) ? p[i1] : 0.f);
        }
    }
    __syncthreads();
    if (threadIdx.x < NEXP) {
        const int e = threadIdx.x;
        float a = 0.f, b = 0.f;
#pragma unroll
        for (int w = 0; w < 4; ++w) { a += s_imp[w][e]; b += s_sel[w][e]; }
        imp_part[blockIdx.x * NEXP + e] = a;
        sel_part[blockIdx.x * NEXP + e] = b;
    }
}

// ---------------------------------------------------------------------------
// Deterministic rank scan; row_token tail fill; zeroes xbf pad row + flags.
// ctrs: [0]=pool, [1..80]=hdone, [81..144]=w2flag
// ---------------------------------------------------------------------------
__global__ __launch_bounds__(1024) void scan_kernel(
    const int* __restrict__ flat_e, int* __restrict__ slot_rank,
    int* __restrict__ row_token, int* __restrict__ n_kept,
    int* __restrict__ cnt_full, unsigned short* __restrict__ xbf_pad,
    int* __restrict__ ctrs)
{
    __shared__ int wave_tot[16][NEXP];
    __shared__ int base[NEXP];
    const int tid = threadIdx.x, lane = tid & 63, w = tid >> 6;
    if (tid < NEXP) base[tid] = 0;
    if (tid < 145) ctrs[tid] = 0;
    for (int i = tid; i < DMODEL; i += 1024) xbf_pad[i] = 0;  // zero pad row
    __syncthreads();
    const unsigned long long ltmask =
        (lane == 0) ? 0ull : (~0ull >> (64 - lane));
    for (int chunk = 0; chunk < (N_TOK * TOPK) / 1024; ++chunk) {
        const int s = chunk * 1024 + tid;
        const int e = flat_e[s];
        int prefix = 0;
#pragma unroll
        for (int ee = 0; ee < NEXP; ++ee) {
            unsigned long long m = __ballot(e == ee);
            if (ee == e) prefix = __popcll(m & ltmask);
            if (lane == 0) wave_tot[w][ee] = __popcll(m);
        }
        __syncthreads();
        int before = base[e];
        for (int ww = 0; ww < w; ++ww) before += wave_tot[ww][e];
        const int rank = before + prefix;
        slot_rank[s] = rank;
        if (rank < CAP) row_token[e * CAP + rank] = s >> 1;
        __syncthreads();
        if (tid < NEXP) {
            int add = 0;
#pragma unroll
            for (int ww = 0; ww < 16; ++ww) add += wave_tot[ww][tid];
            base[tid] += add;
        }
        __syncthreads();
    }
    for (int i = tid; i < NEXP * CAP; i += 1024) {
        const int ee = i / CAP;
        const int r = i - ee * CAP;
        const int ne = base[ee] < CAP ? base[ee] : CAP;
        if (r >= ne) row_token[i] = N_TOK;
    }
    if (tid < NEXP) {
        n_kept[tid] = min(base[tid], CAP);
        cnt_full[tid] = base[tid];
    }
}

// ---------------------------------------------------------------------------
// W1 [E][D][H] f32 -> w1t [E][H][D] bf16 (separate kernel — on G1's critical
// path, runs at full BW with all CUs; 64x64 LDS transpose, nt f32 loads)
// ---------------------------------------------------------------------------
__global__ __launch_bounds__(256) void transpose_cvt(
    const float* __restrict__ W, unsigned short* __restrict__ Wt,
    const int R, const int Cdim)
{
    __shared__ unsigned short s[64][66];
    const int e = blockIdx.z;
    const int c0 = blockIdx.x * 64, r0 = blockIdx.y * 64;
    const float* We = W + (size_t)e * R * Cdim;
    unsigned short* Wte = Wt + (size_t)e * R * Cdim;
    const int tid = threadIdx.x;
    const int lr = tid >> 6;
    const int lc = tid & 63;
#pragma unroll
    for (int i = 0; i < 16; ++i)
        s[lr + i * 4][lc] =
            f2b(__builtin_nontemporal_load(&We[(size_t)(r0 + lr + i * 4) * Cdim + c0 + lc]));
    __syncthreads();
#pragma unroll
    for (int pass = 0; pass < 2; ++pass) {
        const int cc = (tid >> 3) + pass * 32;
        const int rq = (tid & 7) * 8;
        unsigned short v[8];
#pragma unroll
        for (int k = 0; k < 8; ++k) v[k] = s[rq + k][cc];
        u32x4 o;
        o[0] = v[0] | ((unsigned)v[1] << 16); o[1] = v[2] | ((unsigned)v[3] << 16);
        o[2] = v[4] | ((unsigned)v[5] << 16); o[3] = v[6] | ((unsigned)v[7] << 16);
        *(u32x4*)&Wte[(size_t)(c0 + cc) * R + r0 + rq] = o;
    }
}

// ---------------------------------------------------------------------------
// FUSED persistent-CTA kernel: GEMM1 + W2-transpose + GEMM2, 1344-item pool.
// W2T items sit at pool [64,128): they run (BW-bound) while G1 (MFMA-bound)
// occupies the rest of the machine — no consumer spins, since G2 items start
// only after all 640 G1 items (~170us later). Deps via acquire/release-AGENT
// flags (R11/R12-proven): W2T -> w2flag[e*8+n]; G1 -> hdone[e*10+m];
// G2 waits w2flag==1 && hdone==8. Deterministic; deadlock-free (monotonic
// counter, producers at lower pool indices, all 256 CTAs resident).
// Core K-loop = R9-proven (A dbuf + B tbuf, counted vmcnt(4), tail vmcnt(0)).
// ---------------------------------------------------------------------------
#define VMGATE4() do { asm volatile("s_waitcnt vmcnt(4)" ::: "memory"); \
                       __builtin_amdgcn_sched_barrier(0); } while (0)
#define VMGATE0() do { asm volatile("s_waitcnt vmcnt(0)" ::: "memory"); \
                       __builtin_amdgcn_sched_barrier(0); } while (0)
#define NOGATE() ((void)0)

#define PHASE(mf0, STAGE_STMT, TAIL_STMT) do {                                   \
    bf16x8 a0 = lda(c, (mf0), 0), a1 = lda(c, (mf0), 1);                         \
    bf16x8 a2 = lda(c, (mf0) + 1, 0), a3 = lda(c, (mf0) + 1, 1);                 \
    STAGE_STMT;                                                                  \
    __builtin_amdgcn_s_barrier();                                                \
    asm volatile("s_waitcnt lgkmcnt(0)" ::: "memory");                           \
    __builtin_amdgcn_sched_barrier(0);                                           \
    __builtin_amdgcn_s_setprio(1);                                               \
    _Pragma("unroll")                                                            \
    for (int nf = 0; nf < 4; ++nf) {                                             \
        acc[(mf0)][nf] = __builtin_amdgcn_mfma_f32_16x16x32_bf16(                \
            a0, bfr[nf][0], acc[(mf0)][nf], 0, 0, 0);                            \
        acc[(mf0)][nf] = __builtin_amdgcn_mfma_f32_16x16x32_bf16(                \
            a1, bfr[nf][1], acc[(mf0)][nf], 0, 0, 0);                            \
        acc[(mf0) + 1][nf] = __builtin_amdgcn_mfma_f32_16x16x32_bf16(            \
            a2, bfr[nf][0], acc[(mf0) + 1][nf], 0, 0, 0);                        \
        acc[(mf0) + 1][nf] = __builtin_amdgcn_mfma_f32_16x16x32_bf16(            \
            a3, bfr[nf][1], acc[(mf0) + 1][nf], 0, 0, 0);                        \
    }                                                                            \
    __builtin_amdgcn_s_setprio(0);                                               \
    TAIL_STMT;                                                                   \
    __builtin_amdgcn_s_barrier();                                                \
} while (0)

__global__ __launch_bounds__(512, 1) void mfma_fused(
    const unsigned short* __restrict__ xbf,   // [N+1][DMODEL]
    const float* __restrict__ W2,             // [E][HID][HID] f32
    const unsigned short* __restrict__ w1t,   // [E][HID][DMODEL] (pre-made)
    unsigned short* w2t,                      // [E][HID][HID] (produced here)
    const float* __restrict__ b1, const float* __restrict__ b2,
    unsigned short* hbuf,                     // [E][CAP][HID]
    unsigned short* __restrict__ ybuf,        // [E][CAP][HID]
    const int* __restrict__ row_token, const int* __restrict__ n_kept,
    int* __restrict__ ctr)
{
    // 160 KB exactly: A dbuf [2][32KB] at 0, B tbuf [3][32KB] at 65536.
    __shared__ unsigned short smem[81920];
    int* s_item = (int*)((char*)smem + 163836);   // alias: last 4B of B-buf2
    int* hdone  = ctr + 1;      // 80
    int* w2flag = ctr + 81;     // 64

    const int t = threadIdx.x;
    const int w = t >> 6, lane = t & 63;
    const int wm = w >> 2, wn = w & 3;        // 2 x 4 wave grid
    const int l15 = lane & 15, lq = lane >> 4;
    const int srow_lo = t >> 3;               // staging row-within-64 (0..63)

    // swizzled fragment read offsets (row&4 -> flip byte bit5)
    const int sx = (l15 & 4) << 3;
    const int kbx0 = (lq * 16) ^ sx;
    const int kbx1 = (64 + lq * 16) ^ sx;
    auto lda = [&](int cbuf, int mf, int ks) -> bf16x8 {
        return *(const bf16x8*)((const char*)smem + cbuf * 32768 +
                                (wm * 128 + mf * 16 + l15) * 128 + (ks ? kbx1 : kbx0));
    };
    auto ldb = [&](int cbuf, int nf, int ks) -> bf16x8 {
        return *(const bf16x8*)((const char*)smem + 65536 + cbuf * 32768 +
                                (wn * 64 + nf * 16 + l15) * 128 + (ks ? kbx1 : kbx0));
    };

    for (;;) {
        __syncthreads();                       // all prior smem use complete
        if (t == 0) *s_item = atomicAdd(ctr, 1);
        __syncthreads();
        const int item = *s_item;
        if (item >= NTALL) break;

        // ---------------- pool decode ----------------
        bool g2 = false;
        int gIdx = 0;
        if (item < 64)        { gIdx = item; }
        else if (item < 128)  {
            // ---- W2T item: W2[e][:][n*256..] f32 -> w2t[e][n*256..][:] ----
            const int tIdx = item - 64;
            const int e = tIdx >> 3, n = tIdx & 7;
            const float* Wsrc = W2 + (size_t)e * HID * HID + n * 256;
            unsigned short* Wdst = w2t + ((size_t)e * HID + n * 256) * HID;
            unsigned short (*ts)[66] = (unsigned short(*)[66])smem;
            const int lr = t >> 6, lc = t & 63;        // load coords
            const int cc = t >> 3, rq = (t & 7) * 8;   // store coords
            for (int kb = 0; kb < HID; kb += 64) {
                for (int nb = 0; nb < 4; ++nb) {
                    __syncthreads();
#pragma unroll
                    for (int i = 0; i < 8; ++i)
                        ts[lr + i * 8][lc] = f2b(__builtin_nontemporal_load(
                            &Wsrc[(size_t)(kb + lr + i * 8) * HID + nb * 64 + lc]));
                    __syncthreads();
                    unsigned short v[8];
#pragma unroll
                    for (int k2 = 0; k2 < 8; ++k2) v[k2] = ts[rq + k2][cc];
                    u32x4 o;
                    o[0] = v[0] | ((unsigned)v[1] << 16);
                    o[1] = v[2] | ((unsigned)v[3] << 16);
                    o[2] = v[4] | ((unsigned)v[5] << 16);
                    o[3] = v[6] | ((unsigned)v[7] << 16);
                    *(u32x4*)&Wdst[(size_t)(nb * 64 + cc) * HID + kb + rq] = o;
                }
            }
            __syncthreads();   // drains vmcnt(0): stores visible in L2
            if (t == 0)
                __hip_atomic_fetch_add(&w2flag[tIdx], 1, __ATOMIC_RELEASE,
                                       __HIP_MEMORY_SCOPE_AGENT);
            continue;
        }
        else if (item < 704)  { gIdx = item - 64; }
        else                  { gIdx = item - 704; g2 = true; }

        // ---------------- GEMM item ----------------
        const int e = gIdx / 80;
        const int rem = gIdx - e * 80;
        const int m = rem % 10;
        const int n = rem / 10;
        const int m0 = m * 256, n0 = n * 256;
        if (m0 >= n_kept[e]) continue;         // same skip set for both GEMMs

        if (g2) {
            if (t == 0) {
                while (__hip_atomic_load(&w2flag[e * 8 + n], __ATOMIC_ACQUIRE,
                                         __HIP_MEMORY_SCOPE_AGENT) < 1)
                    __builtin_amdgcn_s_sleep(8);
                while (__hip_atomic_load(&hdone[e * 10 + m], __ATOMIC_ACQUIRE,
                                         __HIP_MEMORY_SCOPE_AGENT) < 8)
                    __builtin_amdgcn_s_sleep(8);
            }
            __syncthreads();                   // order acquires before staging
        }

        const int Kdim = g2 ? HID : DMODEL;
        const int NT = Kdim >> 6;
        const unsigned short* A  = g2 ? hbuf : xbf;
        const unsigned short* Wt = g2 ? w2t : w1t;

        long abase[2][2], bbase[2][2];
#pragma unroll
        for (int h = 0; h < 2; ++h) {
#pragma unroll
            for (int cc2 = 0; cc2 < 2; ++cc2) {
                const int srow = h * 128 + cc2 * 64 + srow_lo;
                const int skoff = ((t & 7) * 8) ^ ((srow & 4) << 2);  // inv-swz
                long ar;
                if (g2) ar = ((long)e * CAP + m0 + srow) * (long)Kdim;
                else    ar = (long)row_token[e * CAP + m0 + srow] * Kdim;
                abase[h][cc2] = ar + skoff;
                bbase[h][cc2] = ((long)e * HID + n0 + srow) * (long)Kdim + skoff;
            }
        }
        auto stageA = [&](int buf, int h0, int ktile) {
            const long ko = (long)ktile * 64;
            char* base = (char*)smem + buf * 32768 + h0 * 16384 + w * 1024;
            gload_lds16(A + (h0 ? abase[1][0] : abase[0][0]) + ko, base);
            gload_lds16(A + (h0 ? abase[1][1] : abase[0][1]) + ko, base + 8192);
        };
        auto stageB = [&](int buf, int h0, int ktile) {
            const long ko = (long)ktile * 64;
            char* base = (char*)smem + 65536 + buf * 32768 + h0 * 16384 + w * 1024;
            gload_lds16(Wt + (h0 ? bbase[1][0] : bbase[0][0]) + ko, base);
            gload_lds16(Wt + (h0 ? bbase[1][1] : bbase[0][1]) + ko, base + 8192);
        };

        f32x4 acc[8][4];
#pragma unroll
        for (int mm = 0; mm < 8; ++mm)
#pragma unroll
            for (int nn = 0; nn < 4; ++nn) acc[mm][nn] = (f32x4)0.f;

        // prologue: A(0)->abuf0, B(0)->bbuf0, B(1)->bbuf1
        stageA(0, 0, 0); stageA(0, 1, 0);
        stageB(0, 0, 0); stageB(0, 1, 0);
        stageB(1, 0, 1); stageB(1, 1, 1);
        VMGATE4();
        __builtin_amdgcn_s_barrier();

        int bcur = 0;
        for (int kt = 0; kt < NT; ++kt) {
            const int c = kt & 1, o = c ^ 1;
            const int ktA = kt + 1;
            const int ktB = kt + 2;
            int bst = bcur + 2; if (bst >= 3) bst -= 3;

            bf16x8 bfr[4][2];
#pragma unroll
            for (int nf = 0; nf < 4; ++nf) {
                bfr[nf][0] = ldb(bcur, nf, 0);
                bfr[nf][1] = ldb(bcur, nf, 1);
            }
            PHASE(0, if (ktA < NT) stageA(o, 0, ktA), NOGATE());
            PHASE(2, if (ktA < NT) stageA(o, 1, ktA), NOGATE());
            PHASE(4, if (ktB < NT) stageB(bst, 0, ktB), NOGATE());
            if (ktB < NT) {
                PHASE(6, stageB(bst, 1, ktB), VMGATE4());
            } else {
                PHASE(6, NOGATE(), VMGATE0());
            }
            bcur = (bcur == 2) ? 0 : bcur + 1;
        }

        // epilogue: bias (+ GELU for G1); plain stores (R11-proven)
        const float* be = (g2 ? b2 : b1) + (size_t)e * HID;
        unsigned short* outp = g2 ? ybuf : hbuf;
        float bv[4];
#pragma unroll
        for (int nf = 0; nf < 4; ++nf)
            bv[nf] = be[n0 + wn * 64 + nf * 16 + l15];
#pragma unroll
        for (int mf = 0; mf < 8; ++mf) {
#pragma unroll
            for (int j = 0; j < 4; ++j) {
                const int row = m0 + wm * 128 + mf * 16 + lq * 4 + j;
                unsigned short* orow =
                    outp + ((size_t)e * CAP + row) * HID + n0 + wn * 64 + l15;
#pragma unroll
                for (int nf = 0; nf < 4; ++nf) {
                    float v = acc[mf][nf][j] + bv[nf];
                    if (!g2) v = gelu_f(v);
                    orow[nf * 16] = f2b(v);
                }
            }
        }

        if (!g2) {
            __syncthreads();   // drains vmcnt(0): all 8 waves' stores in L2
            if (t == 0)
                __hip_atomic_fetch_add(&hdone[e * 10 + m], 1, __ATOMIC_RELEASE,
                                       __HIP_MEMORY_SCOPE_AGENT);
        }
    }
}

// ---------------------------------------------------------------------------
// Combine: out[t,:] = w0*y[e0,r0,:] + w1*y[e1,r1,:]  (bf16 y, f32 out)
// ---------------------------------------------------------------------------
__global__ __launch_bounds__(256) void combine_kernel(
    const unsigned short* __restrict__ y, const int* __restrict__ flat_e,
    const float* __restrict__ flat_p, const int* __restrict__ slot_rank,
    float* __restrict__ out)
{
    const int t = blockIdx.x;
    const int e0 = flat_e[2 * t], e1 = flat_e[2 * t + 1];
    const int r0 = slot_rank[2 * t], r1 = slot_rank[2 * t + 1];
    const bool k0 = r0 < CAP, k1 = r1 < CAP;
    const float w0 = k0 ? flat_p[2 * t] : 0.f;
    const float w1 = k1 ? flat_p[2 * t + 1] : 0.f;
    const unsigned short* y0 = y + ((size_t)e0 * CAP + (k0 ? r0 : 0)) * HID;
    const unsigned short* y1 = y + ((size_t)e1 * CAP + (k1 ? r1 : 0)) * HID;
    float* orow = out + (size_t)t * HID;
    const int c = threadIdx.x * 8;
    u32x4 av = k0 ? __builtin_nontemporal_load((const u32x4*)(y0 + c)) : (u32x4)0u;
    u32x4 bv = k1 ? __builtin_nontemporal_load((const u32x4*)(y1 + c)) : (u32x4)0u;
    float o[8];
    auto comb2 = [&](unsigned int a, unsigned int b, float* dst) {
        dst[0] = w0 * b2f((unsigned short)(a & 0xffffu)) +
                 w1 * b2f((unsigned short)(b & 0xffffu));
        dst[1] = w0 * b2f((unsigned short)(a >> 16)) +
                 w1 * b2f((unsigned short)(b >> 16));
    };
    comb2(av[0], bv[0], o + 0); comb2(av[1], bv[1], o + 2);
    comb2(av[2], bv[2], o + 4); comb2(av[3], bv[3], o + 6);
    f32x4 o0 = {o[0], o[1], o[2], o[3]};
    f32x4 o1 = {o[4], o[5], o[6], o[7]};
    __builtin_nontemporal_store(o0, (f32x4*)(orow + c));
    __builtin_nontemporal_store(o1, (f32x4*)(orow + c + 4));
}

// ---------------------------------------------------------------------------
__global__ __launch_bounds__(64) void aux_kernel(
    const float* __restrict__ imp_part, const float* __restrict__ sel_part,
    const int* __restrict__ cnt_full, float* __restrict__ out_aux,
    const int nparts)
{
    const int lane = threadIdx.x;
    __shared__ float imp_s[NEXP], sel_s[NEXP];
    for (int e = 0; e < NEXP; ++e) {
        float a = 0.f, b = 0.f;
        for (int i = lane; i < nparts; i += 64) {
            a += imp_part[i * NEXP + e];
            b += sel_part[i * NEXP + e];
        }
#pragma unroll
        for (int off = 32; off > 0; off >>= 1) {
            a += __shfl_xor(a, off);
            b += __shfl_xor(b, off);
        }
        if (lane == 0) { imp_s[e] = a; sel_s[e] = b; }
    }
    __syncthreads();
    if (lane == 0) {
        double mean = 0.0;
        for (int e = 0; e < NEXP; ++e) mean += imp_s[e];
        mean /= NEXP;
        double var = 0.0;
        for (int e = 0; e < NEXP; ++e) {
            const double d = (double)imp_s[e] - mean;
            var += d * d;
        }
        var /= NEXP;
        double load = 0.0;
        for (int e = 0; e < NEXP; ++e)
            load += ((double)cnt_full[e] / N_TOK) * ((double)sel_s[e] / N_TOK);
        load *= NEXP;
        out_aux[0] = (float)(var / (NEXP * NEXP) + load);
    }
}

// ---------------------------------------------------------------------------
extern "C" void kernel_launch(void* const* d_in, const int* in_sizes, int n_in,
                              void* d_out, int out_size, void* d_ws, size_t ws_size,
                              hipStream_t stream) {
    const float* x  = (const float*)d_in[0];
    const float* Wg = (const float*)d_in[1];
    const float* bg = (const float*)d_in[2];
    const float* W1 = (const float*)d_in[3];
    const float* b1 = (const float*)d_in[4];
    const float* W2 = (const float*)d_in[5];
    const float* b2 = (const float*)d_in[6];
    float* out = (float*)d_out;
    (void)in_sizes; (void)n_in; (void)out_size; (void)ws_size;

    char* ws = (char*)d_ws;
    size_t off = 0;
    auto alloc = [&](size_t bytes) -> void* {
        void* p = ws + off;
        off = (off + bytes + 255) & ~(size_t)255;
        return p;
    };
    int*   n_kept    = (int*)alloc(NEXP * sizeof(int));
    int*   cnt_full  = (int*)alloc(NEXP * sizeof(int));
    int*   ctrs      = (int*)alloc(145 * sizeof(int));  // pool + hdone + w2flag
    int*   flat_e    = (int*)alloc((size_t)N_TOK * TOPK * sizeof(int));
    float* flat_p    = (float*)alloc((size_t)N_TOK * TOPK * sizeof(float));
    int*   slot_rank = (int*)alloc((size_t)N_TOK * TOPK * sizeof(int));
    int*   row_tok   = (int*)alloc((size_t)NEXP * CAP * sizeof(int));
    float* imp_part  = (float*)alloc((size_t)(N_TOK / 4) * NEXP * sizeof(float));
    float* sel_part  = (float*)alloc((size_t)(N_TOK / 4) * NEXP * sizeof(float));
    unsigned short* xbf  = (unsigned short*)alloc((size_t)(N_TOK + 1) * DMODEL * 2);
    unsigned short* w1t  = (unsigned short*)alloc((size_t)NEXP * DMODEL * HID * 2);
    unsigned short* w2t  = (unsigned short*)alloc((size_t)NEXP * HID * HID * 2);
    unsigned short* hbuf = (unsigned short*)alloc((size_t)NEXP * CAP * HID * 2);
    unsigned short* ybuf = (unsigned short*)alloc((size_t)NEXP * CAP * HID * 2);

    gate_kernel<<<N_TOK / 4, 256, 0, stream>>>(x, Wg, bg, flat_e, flat_p,
                                               imp_part, sel_part, xbf);
    scan_kernel<<<1, 1024, 0, stream>>>(flat_e, slot_rank, row_tok, n_kept,
                                        cnt_full, xbf + (size_t)N_TOK * DMODEL,
                                        ctrs);

    // W1^T on the critical path: full-BW separate kernel.
    transpose_cvt<<<dim3(HID / 64, DMODEL / 64, NEXP), 256, 0, stream>>>(W1, w1t, DMODEL, HID);

    mfma_fused<<<256, 512, 0, stream>>>(xbf, W2, w1t, w2t, b1, b2,
                                        hbuf, ybuf, row_tok, n_kept, ctrs);

    combine_kernel<<<N_TOK, 256, 0, stream>>>(ybuf, flat_e, flat_p, slot_rank, out);
    aux_kernel<<<1, 64, 0, stream>>>(imp_part, sel_part, cnt_full,
                                     out + (size_t)N_TOK * HID, N_TOK / 4);
}

// Round 14
// 448.849 us; speedup vs baseline: 1.2058x; 1.2058x over previous
//
#include <hip/hip_runtime.h>
#include <math.h>
#include <stdint.h>

#define N_TOK 8192
#define DMODEL 1024
#define HID 2048
#define NEXP 8
#define TOPK 2
#define CAP 2560
#define NT1 640            // GEMM1 tiles: 8e * 10m * 8n
#define NTALL 1280         // + GEMM2 tiles

typedef __bf16 bf16x8 __attribute__((ext_vector_type(8)));
typedef float f32x4 __attribute__((ext_vector_type(4)));
typedef unsigned int u32x4 __attribute__((ext_vector_type(4)));

__device__ __forceinline__ unsigned short f2b(float f) {
    unsigned int u = __builtin_bit_cast(unsigned int, f);
    u += 0x7fffu + ((u >> 16) & 1u);           // round-to-nearest-even
    return (unsigned short)(u >> 16);
}
__device__ __forceinline__ float b2f(unsigned short s) {
    unsigned int u = ((unsigned int)s) << 16;
    return __builtin_bit_cast(float, u);
}

// Branch-free GELU via Abramowitz-Stegun 7.1.26 erf (|err| <= 1.5e-7)
__device__ __forceinline__ float gelu_f(float v) {
    const float ax = fabsf(v) * 0.70710678118654752440f;
    const float t = __builtin_amdgcn_rcpf(1.f + 0.3275911f * ax);
    float poly = ((((1.061405429f * t - 1.453152027f) * t + 1.421413741f) * t
                   - 0.284496736f) * t + 0.254829592f) * t;
    float er = 1.f - poly * __expf(-ax * ax);
    er = (v >= 0.f) ? er : -er;
    return 0.5f * v * (1.f + er);
}

// async global->LDS, 16B per lane. LDS dst is wave-uniform base (+lane*16 in HW).
__device__ __forceinline__ void gload_lds16(const void* g, void* lds) {
    __builtin_amdgcn_global_load_lds(
        (const __attribute__((address_space(1))) unsigned int*)(uintptr_t)g,
        (__attribute__((address_space(3))) unsigned int*)(unsigned int)(uintptr_t)lds,
        16, 0, 0);
}

// ---------------------------------------------------------------------------
// Gating (exact f32, summation order IDENTICAL to R1-R9 — protects routing
// tie behavior) + fused x->bf16 write.
// ---------------------------------------------------------------------------
__global__ __launch_bounds__(256) void gate_kernel(
    const float* __restrict__ x, const float* __restrict__ Wg,
    const float* __restrict__ bg,
    int* __restrict__ flat_e, float* __restrict__ flat_p,
    float* __restrict__ imp_part, float* __restrict__ sel_part,
    unsigned short* __restrict__ xbf)
{
    __shared__ float s_imp[4][NEXP];
    __shared__ float s_sel[4][NEXP];
    const int wave = threadIdx.x >> 6;
    const int lane = threadIdx.x & 63;
    const int t = blockIdx.x * 4 + wave;

    float acc[NEXP];
#pragma unroll
    for (int e = 0; e < NEXP; ++e) acc[e] = 0.f;
    const float* xr = x + (size_t)t * DMODEL;
    unsigned short* xbr = xbf + (size_t)t * DMODEL;
    for (int d = lane; d < DMODEL; d += 64) {
        const float xv = xr[d];
        xbr[d] = f2b(xv);                       // fused convert_x
#pragma unroll
        for (int e = 0; e < NEXP; ++e) acc[e] += xv * Wg[d * NEXP + e];
    }
#pragma unroll
    for (int off = 32; off > 0; off >>= 1) {
#pragma unroll
        for (int e = 0; e < NEXP; ++e) acc[e] += __shfl_xor(acc[e], off);
    }
    float lg[NEXP], mx = -1e30f;
#pragma unroll
    for (int e = 0; e < NEXP; ++e) { lg[e] = acc[e] + bg[e]; mx = fmaxf(mx, lg[e]); }
    float p[NEXP], s = 0.f;
#pragma unroll
    for (int e = 0; e < NEXP; ++e) { p[e] = expf(lg[e] - mx); s += p[e]; }
    const float inv = 1.f / s;
#pragma unroll
    for (int e = 0; e < NEXP; ++e) p[e] *= inv;

    int i0 = 0;
#pragma unroll
    for (int e = 1; e < NEXP; ++e) if (p[e] > p[i0]) i0 = e;
    int i1 = (i0 == 0) ? 1 : 0;
#pragma unroll
    for (int e = 0; e < NEXP; ++e) if (e != i0 && p[e] > p[i1]) i1 = e;

    if (lane == 0) {
        flat_e[2 * t] = i0;  flat_e[2 * t + 1] = i1;
        flat_p[2 * t] = p[i0]; flat_p[2 * t + 1] = p[i1];
#pragma unroll
        for (int e = 0; e < NEXP; ++e) {
            s_imp[wave][e] = p[e];
            s_sel[wave][e] = (e == i0) ? p[i0] : ((e == i1) ? p[i1] : 0.f);
        }
    }
    __syncthreads();
    if (threadIdx.x < NEXP) {
        const int e = threadIdx.x;
        float a = 0.f, b = 0.f;
#pragma unroll
        for (int w = 0; w < 4; ++w) { a += s_imp[w][e]; b += s_sel[w][e]; }
        imp_part[blockIdx.x * NEXP + e] = a;
        sel_part[blockIdx.x * NEXP + e] = b;
    }
}

// ---------------------------------------------------------------------------
// Deterministic rank scan; row_token tail fill; zeroes xbf pad row + ctr/done.
// ---------------------------------------------------------------------------
__global__ __launch_bounds__(1024) void scan_kernel(
    const int* __restrict__ flat_e, int* __restrict__ slot_rank,
    int* __restrict__ row_token, int* __restrict__ n_kept,
    int* __restrict__ cnt_full, unsigned short* __restrict__ xbf_pad,
    int* __restrict__ ctrs)   // ctrs[0]=pool counter, ctrs[1..80]=done flags
{
    __shared__ int wave_tot[16][NEXP];
    __shared__ int base[NEXP];
    const int tid = threadIdx.x, lane = tid & 63, w = tid >> 6;
    if (tid < NEXP) base[tid] = 0;
    if (tid < 81) ctrs[tid] = 0;
    for (int i = tid; i < DMODEL; i += 1024) xbf_pad[i] = 0;  // zero pad row
    __syncthreads();
    const unsigned long long ltmask =
        (lane == 0) ? 0ull : (~0ull >> (64 - lane));
    for (int chunk = 0; chunk < (N_TOK * TOPK) / 1024; ++chunk) {
        const int s = chunk * 1024 + tid;
        const int e = flat_e[s];
        int prefix = 0;
#pragma unroll
        for (int ee = 0; ee < NEXP; ++ee) {
            unsigned long long m = __ballot(e == ee);
            if (ee == e) prefix = __popcll(m & ltmask);
            if (lane == 0) wave_tot[w][ee] = __popcll(m);
        }
        __syncthreads();
        int before = base[e];
        for (int ww = 0; ww < w; ++ww) before += wave_tot[ww][e];
        const int rank = before + prefix;
        slot_rank[s] = rank;
        if (rank < CAP) row_token[e * CAP + rank] = s >> 1;
        __syncthreads();
        if (tid < NEXP) {
            int add = 0;
#pragma unroll
            for (int ww = 0; ww < 16; ++ww) add += wave_tot[ww][tid];
            base[tid] += add;
        }
        __syncthreads();
    }
    for (int i = tid; i < NEXP * CAP; i += 1024) {
        const int ee = i / CAP;
        const int r = i - ee * CAP;
        const int ne = base[ee] < CAP ? base[ee] : CAP;
        if (r >= ne) row_token[i] = N_TOK;
    }
    if (tid < NEXP) {
        n_kept[tid] = min(base[tid], CAP);
        cnt_full[tid] = base[tid];
    }
}

// ---------------------------------------------------------------------------
// W [E][R][C] f32 -> Wt [E][C][R] bf16 (64x64 LDS transpose; nt f32 loads)
// ---------------------------------------------------------------------------
__global__ __launch_bounds__(256) void transpose_cvt(
    const float* __restrict__ W, unsigned short* __restrict__ Wt,
    const int R, const int Cdim)
{
    __shared__ unsigned short s[64][66];
    const int e = blockIdx.z;
    const int c0 = blockIdx.x * 64, r0 = blockIdx.y * 64;
    const float* We = W + (size_t)e * R * Cdim;
    unsigned short* Wte = Wt + (size_t)e * R * Cdim;
    const int tid = threadIdx.x;
    const int lr = tid >> 6;
    const int lc = tid & 63;
#pragma unroll
    for (int i = 0; i < 16; ++i)
        s[lr + i * 4][lc] =
            f2b(__builtin_nontemporal_load(&We[(size_t)(r0 + lr + i * 4) * Cdim + c0 + lc]));
    __syncthreads();
#pragma unroll
    for (int pass = 0; pass < 2; ++pass) {
        const int cc = (tid >> 3) + pass * 32;
        const int rq = (tid & 7) * 8;
        unsigned short v[8];
#pragma unroll
        for (int k = 0; k < 8; ++k) v[k] = s[rq + k][cc];
        u32x4 o;
        o[0] = v[0] | ((unsigned)v[1] << 16); o[1] = v[2] | ((unsigned)v[3] << 16);
        o[2] = v[4] | ((unsigned)v[5] << 16); o[3] = v[6] | ((unsigned)v[7] << 16);
        *(u32x4*)&Wte[(size_t)(c0 + cc) * R + r0 + rq] = o;
    }
}

// ---------------------------------------------------------------------------
// FUSED persistent-CTA GEMM1+GEMM2 (R11 config — best measured, 449 us).
// One 1280-item pool (5.0 items/CTA — no tail quantization). Items 0..639 =
// GEMM1 (gather xbf, GELU -> hbuf); 640..1279 = GEMM2 (hbuf -> ybuf).
// Cross-GEMM dep: GEMM1 tile (e,m,n) release-AGENT adds done[e*10+m] after
// __syncthreads drains its stores; GEMM2 tile acquire-AGENT spins for
// done==8 before staging hbuf (handles non-coherent per-XCD L2s).
// Deadlock-free: counter monotonic, all GEMM1 items in-flight before any
// GEMM2 item is issued. Deterministic: fixed work set, unique output regions.
// Core K-loop: A dbuf + B triple-buffer, counted vmcnt(4), tail vmcnt(0).
// ---------------------------------------------------------------------------
#define VMGATE4() do { asm volatile("s_waitcnt vmcnt(4)" ::: "memory"); \
                       __builtin_amdgcn_sched_barrier(0); } while (0)
#define VMGATE0() do { asm volatile("s_waitcnt vmcnt(0)" ::: "memory"); \
                       __builtin_amdgcn_sched_barrier(0); } while (0)
#define NOGATE() ((void)0)

#define PHASE(mf0, STAGE_STMT, TAIL_STMT) do {                                   \
    bf16x8 a0 = lda(c, (mf0), 0), a1 = lda(c, (mf0), 1);                         \
    bf16x8 a2 = lda(c, (mf0) + 1, 0), a3 = lda(c, (mf0) + 1, 1);                 \
    STAGE_STMT;                                                                  \
    __builtin_amdgcn_s_barrier();                                                \
    asm volatile("s_waitcnt lgkmcnt(0)" ::: "memory");                           \
    __builtin_amdgcn_sched_barrier(0);                                           \
    __builtin_amdgcn_s_setprio(1);                                               \
    _Pragma("unroll")                                                            \
    for (int nf = 0; nf < 4; ++nf) {                                             \
        acc[(mf0)][nf] = __builtin_amdgcn_mfma_f32_16x16x32_bf16(                \
            a0, bfr[nf][0], acc[(mf0)][nf], 0, 0, 0);                            \
        acc[(mf0)][nf] = __builtin_amdgcn_mfma_f32_16x16x32_bf16(                \
            a1, bfr[nf][1], acc[(mf0)][nf], 0, 0, 0);                            \
        acc[(mf0) + 1][nf] = __builtin_amdgcn_mfma_f32_16x16x32_bf16(            \
            a2, bfr[nf][0], acc[(mf0) + 1][nf], 0, 0, 0);                        \
        acc[(mf0) + 1][nf] = __builtin_amdgcn_mfma_f32_16x16x32_bf16(            \
            a3, bfr[nf][1], acc[(mf0) + 1][nf], 0, 0, 0);                        \
    }                                                                            \
    __builtin_amdgcn_s_setprio(0);                                               \
    TAIL_STMT;                                                                   \
    __builtin_amdgcn_s_barrier();                                                \
} while (0)

__global__ __launch_bounds__(512, 1) void mfma_gemm_fused(
    const unsigned short* __restrict__ xbf,   // [N+1][DMODEL]
    const unsigned short* __restrict__ w1t,   // [E][HID][DMODEL]
    const unsigned short* __restrict__ w2t,   // [E][HID][HID]
    const float* __restrict__ b1, const float* __restrict__ b2,
    unsigned short* __restrict__ hbuf,        // [E][CAP][HID]
    unsigned short* __restrict__ ybuf,        // [E][CAP][HID]
    const int* __restrict__ row_token, const int* __restrict__ n_kept,
    int* __restrict__ ctr)   // ctr[0]=pool counter, ctr[1..80]=done flags
{
    // 160 KB exactly: A dbuf [2][32KB] at 0, B tbuf [3][32KB] at 65536.
    __shared__ unsigned short smem[81920];
    int* s_item = (int*)((char*)smem + 163836);   // alias: last 4B of B-buf2
    int* done = ctr + 1;

    const int t = threadIdx.x;
    const int w = t >> 6, lane = t & 63;
    const int wm = w >> 2, wn = w & 3;        // 2 x 4 wave grid
    const int l15 = lane & 15, lq = lane >> 4;
    const int srow_lo = t >> 3;               // staging row-within-64 (0..63)

    // swizzled fragment read offsets (row&4 -> flip byte bit5)
    const int sx = (l15 & 4) << 3;
    const int kbx0 = (lq * 16) ^ sx;
    const int kbx1 = (64 + lq * 16) ^ sx;
    auto lda = [&](int cbuf, int mf, int ks) -> bf16x8 {
        return *(const bf16x8*)((const char*)smem + cbuf * 32768 +
                                (wm * 128 + mf * 16 + l15) * 128 + (ks ? kbx1 : kbx0));
    };
    auto ldb = [&](int cbuf, int nf, int ks) -> bf16x8 {
        return *(const bf16x8*)((const char*)smem + 65536 + cbuf * 32768 +
                                (wn * 64 + nf * 16 + l15) * 128 + (ks ? kbx1 : kbx0));
    };

    for (;;) {
        __syncthreads();                       // all prior smem use complete
        if (t == 0) *s_item = atomicAdd(ctr, 1);
        __syncthreads();
        const int item = *s_item;
        if (item >= NTALL) break;

        const bool g2 = item >= NT1;
        const int it = g2 ? item - NT1 : item;
        const int e = it / 80;
        const int rem = it - e * 80;
        const int m = rem % 10;
        const int n = rem / 10;
        const int m0 = m * 256, n0 = n * 256;
        if (m0 >= n_kept[e]) continue;         // same skip set for both GEMMs

        if (g2) {                              // wait for hbuf panel (e,m)
            if (t == 0) {
                while (__hip_atomic_load(&done[e * 10 + m], __ATOMIC_ACQUIRE,
                                         __HIP_MEMORY_SCOPE_AGENT) < 8)
                    __builtin_amdgcn_s_sleep(8);
            }
            __syncthreads();                   // order acquire before staging
        }

        const int Kdim = g2 ? HID : DMODEL;
        const int NT = Kdim >> 6;
        const unsigned short* A  = g2 ? hbuf : xbf;
        const unsigned short* Wt = g2 ? w2t : w1t;

        // staging source bases (element offsets), per (half h, call cc)
        long abase[2][2], bbase[2][2];
#pragma unroll
        for (int h = 0; h < 2; ++h) {
#pragma unroll
            for (int cc = 0; cc < 2; ++cc) {
                const int srow = h * 128 + cc * 64 + srow_lo;
                const int skoff = ((t & 7) * 8) ^ ((srow & 4) << 2);  // inv-swz
                long ar;
                if (g2) ar = ((long)e * CAP + m0 + srow) * (long)Kdim;
                else    ar = (long)row_token[e * CAP + m0 + srow] * Kdim;
                abase[h][cc] = ar + skoff;
                bbase[h][cc] = ((long)e * HID + n0 + srow) * (long)Kdim + skoff;
            }
        }
        auto stageA = [&](int buf, int h0, int ktile) {
            const long ko = (long)ktile * 64;
            char* base = (char*)smem + buf * 32768 + h0 * 16384 + w * 1024;
            gload_lds16(A + (h0 ? abase[1][0] : abase[0][0]) + ko, base);
            gload_lds16(A + (h0 ? abase[1][1] : abase[0][1]) + ko, base + 8192);
        };
        auto stageB = [&](int buf, int h0, int ktile) {
            const long ko = (long)ktile * 64;
            char* base = (char*)smem + 65536 + buf * 32768 + h0 * 16384 + w * 1024;
            gload_lds16(Wt + (h0 ? bbase[1][0] : bbase[0][0]) + ko, base);
            gload_lds16(Wt + (h0 ? bbase[1][1] : bbase[0][1]) + ko, base + 8192);
        };

        f32x4 acc[8][4];
#pragma unroll
        for (int mm = 0; mm < 8; ++mm)
#pragma unroll
            for (int nn = 0; nn < 4; ++nn) acc[mm][nn] = (f32x4)0.f;

        // prologue: A(0)->abuf0, B(0)->bbuf0, B(1)->bbuf1
        stageA(0, 0, 0); stageA(0, 1, 0);
        stageB(0, 0, 0); stageB(0, 1, 0);
        stageB(1, 0, 1); stageB(1, 1, 1);
        VMGATE4();
        __builtin_amdgcn_s_barrier();

        int bcur = 0;
        for (int kt = 0; kt < NT; ++kt) {
            const int c = kt & 1, o = c ^ 1;
            const int ktA = kt + 1;
            const int ktB = kt + 2;
            int bst = bcur + 2; if (bst >= 3) bst -= 3;

            bf16x8 bfr[4][2];
#pragma unroll
            for (int nf = 0; nf < 4; ++nf) {
                bfr[nf][0] = ldb(bcur, nf, 0);
                bfr[nf][1] = ldb(bcur, nf, 1);
            }
            PHASE(0, if (ktA < NT) stageA(o, 0, ktA), NOGATE());
            PHASE(2, if (ktA < NT) stageA(o, 1, ktA), NOGATE());
            PHASE(4, if (ktB < NT) stageB(bst, 0, ktB), NOGATE());
            if (ktB < NT) {
                PHASE(6, stageB(bst, 1, ktB), VMGATE4());
            } else {
                PHASE(6, NOGATE(), VMGATE0());
            }
            bcur = (bcur == 2) ? 0 : bcur + 1;
        }

        // epilogue: direct stores, bias (+ GELU for GEMM1)
        const float* be = (g2 ? b2 : b1) + (size_t)e * HID;
        unsigned short* outp = g2 ? ybuf : hbuf;
        float bv[4];
#pragma unroll
        for (int nf = 0; nf < 4; ++nf)
            bv[nf] = be[n0 + wn * 64 + nf * 16 + l15];
#pragma unroll
        for (int mf = 0; mf < 8; ++mf) {
#pragma unroll
            for (int j = 0; j < 4; ++j) {
                const int row = m0 + wm * 128 + mf * 16 + lq * 4 + j;
                unsigned short* orow =
                    outp + ((size_t)e * CAP + row) * HID + n0 + wn * 64 + l15;
#pragma unroll
                for (int nf = 0; nf < 4; ++nf) {
                    float v = acc[mf][nf][j] + bv[nf];
                    if (!g2) v = gelu_f(v);
                    orow[nf * 16] = f2b(v);
                }
            }
        }

        if (!g2) {
            __syncthreads();   // drains vmcnt(0): all 8 waves' stores in L2
            if (t == 0)
                __hip_atomic_fetch_add(&done[e * 10 + m], 1, __ATOMIC_RELEASE,
                                       __HIP_MEMORY_SCOPE_AGENT);
        }
    }
}

// ---------------------------------------------------------------------------
// Combine: out[t,:] = w0*y[e0,r0,:] + w1*y[e1,r1,:]  (bf16 y, f32 out)
// ---------------------------------------------------------------------------
__global__ __launch_bounds__(256) void combine_kernel(
    const unsigned short* __restrict__ y, const int* __restrict__ flat_e,
    const float* __restrict__ flat_p, const int* __restrict__ slot_rank,
    float* __restrict__ out)
{
    const int t = blockIdx.x;
    const int e0 = flat_e[2 * t], e1 = flat_e[2 * t + 1];
    const int r0 = slot_rank[2 * t], r1 = slot_rank[2 * t + 1];
    const bool k0 = r0 < CAP, k1 = r1 < CAP;
    const float w0 = k0 ? flat_p[2 * t] : 0.f;
    const float w1 = k1 ? flat_p[2 * t + 1] : 0.f;
    const unsigned short* y0 = y + ((size_t)e0 * CAP + (k0 ? r0 : 0)) * HID;
    const unsigned short* y1 = y + ((size_t)e1 * CAP + (k1 ? r1 : 0)) * HID;
    float* orow = out + (size_t)t * HID;
    const int c = threadIdx.x * 8;
    u32x4 av = k0 ? __builtin_nontemporal_load((const u32x4*)(y0 + c)) : (u32x4)0u;
    u32x4 bv = k1 ? __builtin_nontemporal_load((const u32x4*)(y1 + c)) : (u32x4)0u;
    float o[8];
    auto comb2 = [&](unsigned int a, unsigned int b, float* dst) {
        dst[0] = w0 * b2f((unsigned short)(a & 0xffffu)) +
                 w1 * b2f((unsigned short)(b & 0xffffu));
        dst[1] = w0 * b2f((unsigned short)(a >> 16)) +
                 w1 * b2f((unsigned short)(b >> 16));
    };
    comb2(av[0], bv[0], o + 0); comb2(av[1], bv[1], o + 2);
    comb2(av[2], bv[2], o + 4); comb2(av[3], bv[3], o + 6);
    f32x4 o0 = {o[0], o[1], o[2], o[3]};
    f32x4 o1 = {o[4], o[5], o[6], o[7]};
    __builtin_nontemporal_store(o0, (f32x4*)(orow + c));
    __builtin_nontemporal_store(o1, (f32x4*)(orow + c + 4));
}

// ---------------------------------------------------------------------------
__global__ __launch_bounds__(64) void aux_kernel(
    const float* __restrict__ imp_part, const float* __restrict__ sel_part,
    const int* __restrict__ cnt_full, float* __restrict__ out_aux,
    const int nparts)
{
    const int lane = threadIdx.x;
    __shared__ float imp_s[NEXP], sel_s[NEXP];
    for (int e = 0; e < NEXP; ++e) {
        float a = 0.f, b = 0.f;
        for (int i = lane; i < nparts; i += 64) {
            a += imp_part[i * NEXP + e];
            b += sel_part[i * NEXP + e];
        }
#pragma unroll
        for (int off = 32; off > 0; off >>= 1) {
            a += __shfl_xor(a, off);
            b += __shfl_xor(b, off);
        }
        if (lane == 0) { imp_s[e] = a; sel_s[e] = b; }
    }
    __syncthreads();
    if (lane == 0) {
        double mean = 0.0;
        for (int e = 0; e < NEXP; ++e) mean += imp_s[e];
        mean /= NEXP;
        double var = 0.0;
        for (int e = 0; e < NEXP; ++e) {
            const double d = (double)imp_s[e] - mean;
            var += d * d;
        }
        var /= NEXP;
        double load = 0.0;
        for (int e = 0; e < NEXP; ++e)
            load += ((double)cnt_full[e] / N_TOK) * ((double)sel_s[e] / N_TOK);
        load *= NEXP;
        out_aux[0] = (float)(var / (NEXP * NEXP) + load);
    }
}

// ---------------------------------------------------------------------------
extern "C" void kernel_launch(void* const* d_in, const int* in_sizes, int n_in,
                              void* d_out, int out_size, void* d_ws, size_t ws_size,
                              hipStream_t stream) {
    const float* x  = (const float*)d_in[0];
    const float* Wg = (const float*)d_in[1];
    const float* bg = (const float*)d_in[2];
    const float* W1 = (const float*)d_in[3];
    const float* b1 = (const float*)d_in[4];
    const float* W2 = (const float*)d_in[5];
    const float* b2 = (const float*)d_in[6];
    float* out = (float*)d_out;
    (void)in_sizes; (void)n_in; (void)out_size; (void)ws_size;

    char* ws = (char*)d_ws;
    size_t off = 0;
    auto alloc = [&](size_t bytes) -> void* {
        void* p = ws + off;
        off = (off + bytes + 255) & ~(size_t)255;
        return p;
    };
    int*   n_kept    = (int*)alloc(NEXP * sizeof(int));
    int*   cnt_full  = (int*)alloc(NEXP * sizeof(int));
    int*   ctrs      = (int*)alloc(81 * sizeof(int));  // [0]=pool, [1..80]=done
    int*   flat_e    = (int*)alloc((size_t)N_TOK * TOPK * sizeof(int));
    float* flat_p    = (float*)alloc((size_t)N_TOK * TOPK * sizeof(float));
    int*   slot_rank = (int*)alloc((size_t)N_TOK * TOPK * sizeof(int));
    int*   row_tok   = (int*)alloc((size_t)NEXP * CAP * sizeof(int));
    float* imp_part  = (float*)alloc((size_t)(N_TOK / 4) * NEXP * sizeof(float));
    float* sel_part  = (float*)alloc((size_t)(N_TOK / 4) * NEXP * sizeof(float));
    unsigned short* xbf  = (unsigned short*)alloc((size_t)(N_TOK + 1) * DMODEL * 2);
    unsigned short* w1t  = (unsigned short*)alloc((size_t)NEXP * DMODEL * HID * 2);
    unsigned short* w2t  = (unsigned short*)alloc((size_t)NEXP * HID * HID * 2);
    unsigned short* hbuf = (unsigned short*)alloc((size_t)NEXP * CAP * HID * 2);
    unsigned short* ybuf = (unsigned short*)alloc((size_t)NEXP * CAP * HID * 2);

    gate_kernel<<<N_TOK / 4, 256, 0, stream>>>(x, Wg, bg, flat_e, flat_p,
                                               imp_part, sel_part, xbf);
    scan_kernel<<<1, 1024, 0, stream>>>(flat_e, slot_rank, row_tok, n_kept,
                                        cnt_full, xbf + (size_t)N_TOK * DMODEL,
                                        ctrs);

    transpose_cvt<<<dim3(HID / 64, DMODEL / 64, NEXP), 256, 0, stream>>>(W1, w1t, DMODEL, HID);
    transpose_cvt<<<dim3(HID / 64, HID / 64, NEXP), 256, 0, stream>>>(W2, w2t, HID, HID);

    mfma_gemm_fused<<<256, 512, 0, stream>>>(xbf, w1t, w2t, b1, b2, hbuf, ybuf,
                                             row_tok, n_kept, ctrs);

    combine_kernel<<<N_TOK, 256, 0, stream>>>(ybuf, flat_e, flat_p, slot_rank, out);
    aux_kernel<<<1, 64, 0, stream>>>(imp_part, sel_part, cnt_full,
                                     out + (size_t)N_TOK * HID, N_TOK / 4);
}